// Round 1
// baseline (1828.913 us; speedup 1.0000x reference)
//
#include <hip/hip_runtime.h>

// ============================================================================
// CNF log-density, fused persistent kernel.
//   - DOPRI5, 4 steps, 6 stages/step = 24 f-evals, all fused in one kernel.
//   - Each block: 64 batch rows (4 waves x 16 rows). Wave owns its rows for
//     the entire integration; activations never touch global memory.
//   - GEMMs: mfma_f32_16x16x32_bf16, value+tangent share B fragments.
//   - Weights pre-converted to bf16 "fragment-linear" layout in d_ws so LDS
//     staging is a contiguous 16B/lane copy (frag = ktile*NT + ntile).
//   - RK state in registers in A-fragment layout (row=lane&15, k=quad*8+j).
//   - C->A layout change via wave-private LDS transpose; tanh done in-place
//     in the accumulator so the tangent pass reuses h without recompute.
// ============================================================================

#define DIM   64
#define HID   256
#define BATCH 32768
#define LOG2PI_HALF_SUM 58.8120661251f   // 32 * log(2*pi)

typedef float  floatx4 __attribute__((ext_vector_type(4)));
typedef short  short8  __attribute__((ext_vector_type(8)));

// ---- workspace layout (bytes) ----
#define W1OFF 0          // 2 kt * 16 nt * 1KB  = 32768
#define W2OFF 32768      // 8 kt * 16 nt * 1KB  = 131072
#define W3OFF 163840     // 131072
#define W4OFF 294912     // 8 kt * 4 nt * 1KB   = 32768
#define BOFF  327680     // biases fp32: b1[256] b2[256] b3[256] b4[64]

// ---- LDS layout (bytes) ----
#define BUF0 0
#define BUF1 8192
#define TBOFF 16384
#define TBSTRIDE 264                      // shorts per row (256 + 8 pad)
#define TBWAVE 8448                       // 16 * 264 * 2
#define SMEM_BYTES (16384 + 4*TBWAVE)     // 50176

__device__ __forceinline__ short f2bf(float f) {
    union { float f; unsigned u; } v; v.f = f;
    unsigned r = v.u + 0x7FFFu + ((v.u >> 16) & 1u);   // RTNE
    return (short)(r >> 16);
}

__device__ __forceinline__ float fast_tanh(float x) {
    // tanh(x) = 1 - 2/(exp(2x)+1); v_exp_f32 + v_rcp_f32, ~1e-7 abs err
    float e = __expf(2.0f * x);
    return 1.0f - 2.0f * __builtin_amdgcn_rcpf(e + 1.0f);
}

template <int BYTES>
__device__ __forceinline__ void stage(const char* __restrict__ g, char* l) {
    const int t = threadIdx.x;
#pragma unroll
    for (int off = 0; off < BYTES; off += 4096) {
        *(uint4*)(l + off + t * 16) = *(const uint4*)(g + off + t * 16);
    }
}

// Epilogue for hidden layers: in-place tanh on av, write bf16 h to transpose
// buffer, read back A-frags; then tangent t = (1-h^2)*at, same round-trip.
// Wave-private LDS region: no barrier needed (same-wave DS ops are ordered).
__device__ __forceinline__ void act_transpose(floatx4* av, floatx4* at,
                                              short8* Av, short8* At,
                                              short* tbs, int m, int kq) {
#pragma unroll
    for (int nt = 0; nt < 16; nt++)
#pragma unroll
        for (int i = 0; i < 4; i++) {
            float hv = fast_tanh(av[nt][i]);
            av[nt][i] = hv;                      // keep h for tangent scaling
            tbs[(kq * 4 + i) * TBSTRIDE + nt * 16 + m] = f2bf(hv);
        }
#pragma unroll
    for (int kt = 0; kt < 8; kt++)
        Av[kt] = *(const short8*)&tbs[m * TBSTRIDE + kt * 32 + kq * 8];
#pragma unroll
    for (int nt = 0; nt < 16; nt++)
#pragma unroll
        for (int i = 0; i < 4; i++) {
            float tv = (1.0f - av[nt][i] * av[nt][i]) * at[nt][i];
            tbs[(kq * 4 + i) * TBSTRIDE + nt * 16 + m] = f2bf(tv);
        }
#pragma unroll
    for (int kt = 0; kt < 8; kt++)
        At[kt] = *(const short8*)&tbs[m * TBSTRIDE + kt * 32 + kq * 8];
}

// One ODE function evaluation: dz left in tbf (fp32, stride 68, 16x64),
// returns div = sum_k Jeps*eps for row (lane&15), replicated across quads.
__device__ __forceinline__ float feval(short8 z0, short8 z1, short8 e0, short8 e1,
                                       const float* ef,
                                       const char* __restrict__ ws, char* smem) {
    const int tid  = threadIdx.x;
    const int lane = tid & 63;
    const int wave = tid >> 6;
    const int m  = lane & 15, kq = lane >> 4;
    char* bufs[2] = { smem + BUF0, smem + BUF1 };
    short* tbs = (short*)(smem + TBOFF + wave * TBWAVE);
    float* tbf = (float*)tbs;
    const float* bias = (const float*)(ws + BOFF);
    const int boff = lane * 16;

    floatx4 av[16], at[16];
    short8  Av[8], At[8];
    const floatx4 zero4 = {0.f, 0.f, 0.f, 0.f};

    // ---------------- layer 1: K=64 (2 kt), N=256 ----------------
#pragma unroll
    for (int nt = 0; nt < 16; nt++) {
        float b = bias[nt * 16 + m];
        floatx4 bv = {b, b, b, b};
        av[nt] = bv; at[nt] = zero4;
    }
    stage<8192>(ws + W1OFF, bufs[0]);
    __syncthreads();
#pragma unroll
    for (int c = 0; c < 4; c++) {
        if (c < 3) stage<8192>(ws + W1OFF + (c + 1) * 8192, bufs[(c + 1) & 1]);
        short8 a_v = (c < 2) ? z0 : z1;
        short8 a_t = (c < 2) ? e0 : e1;
        const int half = c & 1;
#pragma unroll
        for (int nt8 = 0; nt8 < 8; nt8++) {
            short8 b = *(const short8*)(bufs[c & 1] + nt8 * 1024 + boff);
            const int nt = half * 8 + nt8;
            av[nt] = __builtin_amdgcn_mfma_f32_16x16x32_bf16(a_v, b, av[nt], 0, 0, 0);
            at[nt] = __builtin_amdgcn_mfma_f32_16x16x32_bf16(a_t, b, at[nt], 0, 0, 0);
        }
        __syncthreads();
    }
    act_transpose(av, at, Av, At, tbs, m, kq);

    // ---------------- layers 2,3: K=256 (8 kt), N=256 ----------------
#pragma unroll 1
    for (int layer = 0; layer < 2; layer++) {
        const char* wb = ws + (layer ? W3OFF : W2OFF);
        const float* bb = bias + 256 + layer * 256;
#pragma unroll
        for (int nt = 0; nt < 16; nt++) {
            float b = bb[nt * 16 + m];
            floatx4 bv = {b, b, b, b};
            av[nt] = bv; at[nt] = zero4;
        }
        stage<8192>(wb, bufs[0]);
        __syncthreads();
#pragma unroll
        for (int c = 0; c < 16; c++) {
            if (c < 15) stage<8192>(wb + (c + 1) * 8192, bufs[(c + 1) & 1]);
            const int kt = c >> 1, half = c & 1;
#pragma unroll
            for (int nt8 = 0; nt8 < 8; nt8++) {
                short8 b = *(const short8*)(bufs[c & 1] + nt8 * 1024 + boff);
                const int nt = half * 8 + nt8;
                av[nt] = __builtin_amdgcn_mfma_f32_16x16x32_bf16(Av[kt], b, av[nt], 0, 0, 0);
                at[nt] = __builtin_amdgcn_mfma_f32_16x16x32_bf16(At[kt], b, at[nt], 0, 0, 0);
            }
            __syncthreads();
        }
        act_transpose(av, at, Av, At, tbs, m, kq);
    }

    // ---------------- layer 4: K=256 (8 kt), N=64 ----------------
    floatx4 a4v[4], a4t[4];
#pragma unroll
    for (int nt = 0; nt < 4; nt++) {
        float b = bias[768 + nt * 16 + m];
        floatx4 bv = {b, b, b, b};
        a4v[nt] = bv; a4t[nt] = zero4;
    }
    stage<4096>(ws + W4OFF, bufs[0]);
    __syncthreads();
#pragma unroll
    for (int kt = 0; kt < 8; kt++) {
        if (kt < 7) stage<4096>(ws + W4OFF + (kt + 1) * 4096, bufs[(kt + 1) & 1]);
#pragma unroll
        for (int nt = 0; nt < 4; nt++) {
            short8 b = *(const short8*)(bufs[kt & 1] + nt * 1024 + boff);
            a4v[nt] = __builtin_amdgcn_mfma_f32_16x16x32_bf16(Av[kt], b, a4v[nt], 0, 0, 0);
            a4t[nt] = __builtin_amdgcn_mfma_f32_16x16x32_bf16(At[kt], b, a4t[nt], 0, 0, 0);
        }
        __syncthreads();
    }

    // Jeps: transpose (C->A layout) then dot with eps fragments
#pragma unroll
    for (int nt = 0; nt < 4; nt++)
#pragma unroll
        for (int i = 0; i < 4; i++)
            tbf[(kq * 4 + i) * 68 + nt * 16 + m] = a4t[nt][i];
    float div = 0.f;
#pragma unroll
    for (int kt2 = 0; kt2 < 2; kt2++) {
#pragma unroll
        for (int jj = 0; jj < 8; jj += 4) {
            floatx4 jv = *(const floatx4*)&tbf[m * 68 + kt2 * 32 + kq * 8 + jj];
            div += jv.x * ef[kt2 * 8 + jj]     + jv.y * ef[kt2 * 8 + jj + 1]
                 + jv.z * ef[kt2 * 8 + jj + 2] + jv.w * ef[kt2 * 8 + jj + 3];
        }
    }
    div += __shfl_xor(div, 16, 64);
    div += __shfl_xor(div, 32, 64);

    // dz: transpose into tbf for the caller to read back in frag layout
#pragma unroll
    for (int nt = 0; nt < 4; nt++)
#pragma unroll
        for (int i = 0; i < 4; i++)
            tbf[(kq * 4 + i) * 68 + nt * 16 + m] = a4v[nt][i];
    return div;
}

__global__ void __launch_bounds__(256, 1)
cnf_main(const float* __restrict__ x, const float* __restrict__ eps,
         const char* __restrict__ ws, float* __restrict__ out) {
    extern __shared__ char smem[];
    const int tid  = threadIdx.x;
    const int lane = tid & 63;
    const int wave = tid >> 6;
    const int m  = lane & 15, kq = lane >> 4;
    const int row = blockIdx.x * 64 + wave * 16 + m;
    float* tbf = (float*)(smem + TBOFF + wave * TBWAVE);

    float y[16], ef[16];
#pragma unroll
    for (int kt = 0; kt < 2; kt++)
#pragma unroll
        for (int q = 0; q < 2; q++) {
            floatx4 vx = *(const floatx4*)(x   + row * DIM + kt * 32 + kq * 8 + q * 4);
            floatx4 ve = *(const floatx4*)(eps + row * DIM + kt * 32 + kq * 8 + q * 4);
#pragma unroll
            for (int j = 0; j < 4; j++) {
                y[kt * 8 + q * 4 + j]  = vx[j];
                ef[kt * 8 + q * 4 + j] = ve[j];
            }
        }
    short8 e0, e1;
#pragma unroll
    for (int j = 0; j < 8; j++) { e0[j] = f2bf(ef[j]); e1[j] = f2bf(ef[8 + j]); }

    float kk1[16], kk2[16], kk3[16], kk4[16], kk5[16], kk6[16], zs[16];
    float ylogp = 0.f;

    auto pack2 = [&](const float* v, short8& lo, short8& hi) {
#pragma unroll
        for (int j = 0; j < 8; j++) { lo[j] = f2bf(v[j]); hi[j] = f2bf(v[8 + j]); }
    };
    auto readk = [&](float* K) {
#pragma unroll
        for (int kt = 0; kt < 2; kt++) {
            floatx4 r0 = *(const floatx4*)&tbf[m * 68 + kt * 32 + kq * 8];
            floatx4 r1 = *(const floatx4*)&tbf[m * 68 + kt * 32 + kq * 8 + 4];
#pragma unroll
            for (int j = 0; j < 4; j++) { K[kt * 8 + j] = r0[j]; K[kt * 8 + 4 + j] = r1[j]; }
        }
    };

#pragma unroll 1
    for (int step = 0; step < 4; step++) {
        short8 z0, z1;
        pack2(y, z0, z1);
        const float d1 = feval(z0, z1, e0, e1, ef, ws, smem); readk(kk1);
#pragma unroll
        for (int i = 0; i < 16; i++) zs[i] = y[i] + 0.05f * kk1[i];
        pack2(zs, z0, z1);
        const float d2 = feval(z0, z1, e0, e1, ef, ws, smem); readk(kk2);
        (void)d2;
#pragma unroll
        for (int i = 0; i < 16; i++) zs[i] = y[i] + 0.01875f * kk1[i] + 0.05625f * kk2[i];
        pack2(zs, z0, z1);
        const float d3 = feval(z0, z1, e0, e1, ef, ws, smem); readk(kk3);
#pragma unroll
        for (int i = 0; i < 16; i++)
            zs[i] = y[i] + 0.244444444f * kk1[i] - 0.933333333f * kk2[i] + 0.888888889f * kk3[i];
        pack2(zs, z0, z1);
        const float d4 = feval(z0, z1, e0, e1, ef, ws, smem); readk(kk4);
#pragma unroll
        for (int i = 0; i < 16; i++)
            zs[i] = y[i] + 0.738149672f * kk1[i] - 2.898948331f * kk2[i]
                         + 2.455723213f * kk3[i] - 0.072702332f * kk4[i];
        pack2(zs, z0, z1);
        const float d5 = feval(z0, z1, e0, e1, ef, ws, smem); readk(kk5);
#pragma unroll
        for (int i = 0; i < 16; i++)
            zs[i] = y[i] + 0.711568813f * kk1[i] - 2.689393939f * kk2[i]
                         + 2.226605679f * kk3[i] + 0.069602273f * kk4[i]
                         - 0.068382826f * kk5[i];
        pack2(zs, z0, z1);
        const float d6 = feval(z0, z1, e0, e1, ef, ws, smem); readk(kk6);

#pragma unroll
        for (int i = 0; i < 16; i++)
            y[i] += 0.022786458f * kk1[i] + 0.112309075f * kk3[i] + 0.162760417f * kk4[i]
                  - 0.080593989f * kk5[i] + 0.032738095f * kk6[i];
        ylogp -= 0.022786458f * d1 + 0.112309075f * d3 + 0.162760417f * d4
               - 0.080593989f * d5 + 0.032738095f * d6;
    }

    float nrm = 0.f;
#pragma unroll
    for (int i = 0; i < 16; i++) nrm += y[i] * y[i];
    nrm += __shfl_xor(nrm, 16, 64);
    nrm += __shfl_xor(nrm, 32, 64);
    float res = -0.5f * nrm - LOG2PI_HALF_SUM - ylogp;
    if (lane < 16) out[blockIdx.x * 64 + wave * 16 + lane] = res;
}

// ---- weight pre-shuffle: fp32 [N][K] -> bf16 fragment-linear ----
// frag = ktile*NT + ntile; lane l holds W[ntile*16+(l&15)][ktile*32+(l>>4)*8 + 0..7]
__global__ void prep_w(const float* __restrict__ W, short* __restrict__ outp,
                       int K, int NT, int KT) {
    int slot  = blockIdx.x * 256 + threadIdx.x;
    int total = KT * NT * 64;
    if (slot >= total) return;
    int lane  = slot & 63, frag = slot >> 6;
    int ntile = frag % NT, ktile = frag / NT;
    int n = ntile * 16 + (lane & 15);
    int k = ktile * 32 + (lane >> 4) * 8;
    short8 v;
#pragma unroll
    for (int j = 0; j < 8; j++) v[j] = f2bf(W[n * K + k + j]);
    *(short8*)(outp + slot * 8) = v;
}

__global__ void prep_b(const float* __restrict__ b1, const float* __restrict__ b2,
                       const float* __restrict__ b3, const float* __restrict__ b4,
                       float* __restrict__ dst) {
    int i = blockIdx.x * 256 + threadIdx.x;
    if (i < 256)      dst[i] = b1[i];
    else if (i < 512) dst[i] = b2[i - 256];
    else if (i < 768) dst[i] = b3[i - 512];
    else if (i < 832) dst[i] = b4[i - 768];
}

extern "C" void kernel_launch(void* const* d_in, const int* in_sizes, int n_in,
                              void* d_out, int out_size, void* d_ws, size_t ws_size,
                              hipStream_t stream) {
    const float* x   = (const float*)d_in[0];
    const float* eps = (const float*)d_in[1];
    const float* W1  = (const float*)d_in[2];
    const float* b1  = (const float*)d_in[3];
    const float* W2  = (const float*)d_in[4];
    const float* b2  = (const float*)d_in[5];
    const float* W3  = (const float*)d_in[6];
    const float* b3  = (const float*)d_in[7];
    const float* W4  = (const float*)d_in[8];
    const float* b4  = (const float*)d_in[9];
    char*  ws  = (char*)d_ws;
    float* out = (float*)d_out;

    prep_w<<<(2 * 16 * 64 + 255) / 256, 256, 0, stream>>>(W1, (short*)(ws + W1OFF), 64, 16, 2);
    prep_w<<<(8 * 16 * 64 + 255) / 256, 256, 0, stream>>>(W2, (short*)(ws + W2OFF), 256, 16, 8);
    prep_w<<<(8 * 16 * 64 + 255) / 256, 256, 0, stream>>>(W3, (short*)(ws + W3OFF), 256, 16, 8);
    prep_w<<<(8 * 4 * 64 + 255) / 256, 256, 0, stream>>>(W4, (short*)(ws + W4OFF), 256, 4, 8);
    prep_b<<<4, 256, 0, stream>>>(b1, b2, b3, b4, (float*)(ws + BOFF));

    cnf_main<<<BATCH / 64, 256, SMEM_BYTES, stream>>>(x, eps, ws, out);
}